// Round 4
// baseline (134.054 us; speedup 1.0000x reference)
//
#include <hip/hip_runtime.h>
#include <hip/hip_bf16.h>

#define BB 8
#define CC 16
#define EE 256
#define HH 256
#define WW 256
#define HPAD 258
#define WPAD 258
#define EMB_ROW (EE*9)

typedef __attribute__((ext_vector_type(8)))  __bf16 bf16x8;
typedef __attribute__((ext_vector_type(16))) float  f32x16;

// ---- ws layout ----
// X_t : [BB][HPAD][WPAD][CC] bf16  -> 17,040,384 B (offset 0)
// W_g : [BB][9][EE][CC]      bf16  ->    589,824 B
#define XT_BYTES  17040384
#define WS_NEEDED (XT_BYTES + 589824)

#define NX (BB*HPAD*WPAD)      // 532512 x-transpose items
#define NW (BB*9*EE*CC)        // 294912 weight-gather items
#define PREP_BLOCKS ((NX + NW + 255) / 256)

// ---------------- merged prep: x-transpose + weight gather ----------------
__global__ __launch_bounds__(256) void prep_all(const float* __restrict__ x,
                                                const int* __restrict__ indices,
                                                const float* __restrict__ emb,
                                                __hip_bfloat16* __restrict__ Xt,
                                                __hip_bfloat16* __restrict__ Wg) {
    const int t = blockIdx.x * 256 + threadIdx.x;
    if (t < NX) {
        const int wp = t % WPAD;
        const int r  = t / WPAD;
        const int hp = r % HPAD;
        const int b  = r / HPAD;
        union { __hip_bfloat16 v[16]; uint4 q[2]; } u;
        if (hp >= 1 && hp <= HH && wp >= 1 && wp <= WW) {
            const float* xp = x + (size_t)b * CC * HH * WW + (size_t)(hp - 1) * WW + (wp - 1);
            #pragma unroll
            for (int c = 0; c < CC; ++c)
                u.v[c] = __float2bfloat16(__builtin_nontemporal_load(xp + (size_t)c * HH * WW));
        } else {
            #pragma unroll
            for (int c = 0; c < CC; ++c) u.v[c] = __float2bfloat16(0.f);
        }
        uint4* dst = reinterpret_cast<uint4*>(Xt + (size_t)t * CC);
        dst[0] = u.q[0];   // cached stores: conv wants these in L2/L3
        dst[1] = u.q[1];
    } else if (t < NX + NW) {
        const int u  = t - NX;
        const int c  = u & 15;
        const int e  = (u >> 4) & 255;
        const int bt = u >> 12;          // b*9 + tap
        const int tap = bt % 9;
        const int b   = bt / 9;
        Wg[u] = __float2bfloat16(emb[(size_t)indices[b * CC + c] * EMB_ROW + e * 9 + tap]);
    }
}

// ---------------- main: implicit-GEMM conv via MFMA ----------------
// grid: (BB, 32, 8)  block: 512 (8 waves). Block = 32e x 256w x 8h.
// All waves share the e-tile (same A-frags, L1 broadcast); wave wid owns
// w0 = wid*32. Per-block stores: 32 e-rows x 8h x 1KB = contiguous 8KB/e.
__global__ __launch_bounds__(512) void conv_mfma(
    const __bf16* __restrict__ Xt,      // [BB][HPAD][WPAD][CC]
    const __bf16* __restrict__ Wg,      // [BB][9][EE][CC]
    const float*  __restrict__ bias,    // [EE]
    float*        __restrict__ out)     // [BB][EE][HH][WW]
{
    const int b  = blockIdx.x;          // batch fastest -> XCD k handles batch k
    const int hc = blockIdx.y;          // h-chunk of 8 rows
    const int ez = blockIdx.z;          // e-tile of 32

    const int tid   = threadIdx.x;
    const int lane  = tid & 63;
    const int wid   = tid >> 6;         // 0..7
    const int l31   = lane & 31;
    const int lhalf = lane >> 5;

    const int e0 = ez * 32;
    const int w0 = wid * 32;
    const int h0 = hc * 8;

    // A fragments: 9 taps, lane l: e = e0 + l31, c = lhalf*8 .. +8
    bf16x8 afrag[9];
    #pragma unroll
    for (int tap = 0; tap < 9; ++tap) {
        const __bf16* ap = Wg + ((size_t)(b * 9 + tap) * EE + (e0 + l31)) * CC + lhalf * 8;
        afrag[tap] = *reinterpret_cast<const bf16x8*>(ap);
    }

    // bias per C/D reg (erow = (r&3) + 8*(r>>2) + 4*lhalf)
    float bv[16];
    #pragma unroll
    for (int r = 0; r < 16; ++r) {
        const int erow = (r & 3) + 8 * (r >> 2) + 4 * lhalf;
        bv[r] = bias[e0 + erow];
    }

    for (int h = h0; h < h0 + 8; ++h) {
        f32x16 acc;
        #pragma unroll
        for (int r = 0; r < 16; ++r) acc[r] = bv[r];

        #pragma unroll
        for (int kh = 0; kh < 3; ++kh) {
            const __bf16* bp = Xt + ((size_t)(b * HPAD + (h + kh)) * WPAD + w0 + l31) * CC + lhalf * 8;
            #pragma unroll
            for (int kw = 0; kw < 3; ++kw) {
                bf16x8 bfrag = *reinterpret_cast<const bf16x8*>(bp + kw * CC);
                acc = __builtin_amdgcn_mfma_f32_32x32x16_bf16(afrag[kh * 3 + kw], bfrag, acc, 0, 0, 0);
            }
        }

        // nt stores: stream output past L2, keep Xt resident
        #pragma unroll
        for (int r = 0; r < 16; ++r) {
            const int erow = (r & 3) + 8 * (r >> 2) + 4 * lhalf;
            __builtin_nontemporal_store(acc[r],
                &out[((size_t)(b * EE + e0 + erow) * HH + h) * WW + w0 + l31]);
        }
    }
}

// ---------------- fallback: f32 direct conv (if ws too small) ----------------
#define EBLK 4
#define RBLK 4
__global__ __launch_bounds__(256) void conv_emb_f32(
    const float* __restrict__ x, const int* __restrict__ indices,
    const float* __restrict__ emb, const float* __restrict__ bias,
    float* __restrict__ out)
{
    const int w  = threadIdx.x;
    const int h0 = blockIdx.x * RBLK;
    const int e0 = blockIdx.y * EBLK;
    const int b  = blockIdx.z;

    float acc[RBLK][EBLK];
    #pragma unroll
    for (int r = 0; r < RBLK; ++r)
        #pragma unroll
        for (int e = 0; e < EBLK; ++e) acc[r][e] = 0.f;

    #pragma unroll 1
    for (int c = 0; c < CC; ++c) {
        const float* xp = x + (size_t)(b * CC + c) * HH * WW;
        float xv[RBLK + 2][3];
        #pragma unroll
        for (int ir = 0; ir < RBLK + 2; ++ir) {
            const int h = h0 + ir - 1;
            if (h >= 0 && h < HH) {
                const float* row = xp + (size_t)h * WW;
                xv[ir][1] = row[w];
                xv[ir][0] = (w > 0)      ? row[w - 1] : 0.f;
                xv[ir][2] = (w < WW - 1) ? row[w + 1] : 0.f;
            } else {
                xv[ir][0] = 0.f; xv[ir][1] = 0.f; xv[ir][2] = 0.f;
            }
        }
        const int idx = indices[b * CC + c];
        const float* wp = emb + (size_t)idx * EMB_ROW + e0 * 9;
        #pragma unroll
        for (int e = 0; e < EBLK; ++e)
            #pragma unroll
            for (int kh = 0; kh < 3; ++kh)
                #pragma unroll
                for (int kw = 0; kw < 3; ++kw) {
                    const float wv = wp[e * 9 + kh * 3 + kw];
                    #pragma unroll
                    for (int r = 0; r < RBLK; ++r)
                        acc[r][e] += xv[r + kh][kw] * wv;
                }
    }
    #pragma unroll
    for (int e = 0; e < EBLK; ++e) {
        const float bvv = bias[e0 + e];
        #pragma unroll
        for (int r = 0; r < RBLK; ++r)
            out[((size_t)(b * EE + e0 + e) * HH + (h0 + r)) * WW + w] = acc[r][e] + bvv;
    }
}

extern "C" void kernel_launch(void* const* d_in, const int* in_sizes, int n_in,
                              void* d_out, int out_size, void* d_ws, size_t ws_size,
                              hipStream_t stream) {
    const float* x       = (const float*)d_in[0];
    const int*   indices = (const int*)  d_in[1];
    const float* emb     = (const float*)d_in[2];
    const float* bias    = (const float*)d_in[3];
    float*       out     = (float*)d_out;

    if (ws_size < (size_t)WS_NEEDED) {
        dim3 grid(HH / RBLK, EE / EBLK, BB);
        conv_emb_f32<<<grid, dim3(256), 0, stream>>>(x, indices, emb, bias, out);
        return;
    }

    __hip_bfloat16* Xt = (__hip_bfloat16*)d_ws;
    __hip_bfloat16* Wg = (__hip_bfloat16*)((char*)d_ws + XT_BYTES);

    prep_all<<<dim3(PREP_BLOCKS), dim3(256), 0, stream>>>(x, indices, emb, Xt, Wg);

    conv_mfma<<<dim3(BB, 32, 8), dim3(512), 0, stream>>>(
        (const __bf16*)Xt, (const __bf16*)Wg, bias, out);
}

// Round 6
// 119.440 us; speedup vs baseline: 1.1224x; 1.1224x over previous
//
#include <hip/hip_runtime.h>
#include <hip/hip_bf16.h>

#define BB 8
#define CC 16
#define EE 256
#define HH 256
#define WW 256
#define HPAD 258
#define WPAD 258
#define EMB_ROW (EE*9)

typedef __attribute__((ext_vector_type(8)))  __bf16 bf16x8;
typedef __attribute__((ext_vector_type(16))) float  f32x16;
typedef __attribute__((ext_vector_type(4)))  float  f32x4;

// ---- ws layout ----
#define XT_BYTES  17040384            // [BB][HPAD][WPAD][CC] bf16
#define WS_NEEDED (XT_BYTES + 589824) // + [BB][9][EE][CC] bf16

#define NX (BB*HPAD*WPAD)
#define NW (BB*9*EE*CC)
#define PREP_BLOCKS ((NX + NW + 255) / 256)

// ---------------- merged prep: x-transpose + weight gather ----------------
__global__ __launch_bounds__(256) void prep_all(const float* __restrict__ x,
                                                const int* __restrict__ indices,
                                                const float* __restrict__ emb,
                                                __hip_bfloat16* __restrict__ Xt,
                                                __hip_bfloat16* __restrict__ Wg) {
    const int t = blockIdx.x * 256 + threadIdx.x;
    if (t < NX) {
        const int wp = t % WPAD;
        const int r  = t / WPAD;
        const int hp = r % HPAD;
        const int b  = r / HPAD;
        union { __hip_bfloat16 v[16]; uint4 q[2]; } u;
        if (hp >= 1 && hp <= HH && wp >= 1 && wp <= WW) {
            const float* xp = x + (size_t)b * CC * HH * WW + (size_t)(hp - 1) * WW + (wp - 1);
            #pragma unroll
            for (int c = 0; c < CC; ++c)
                u.v[c] = __float2bfloat16(xp[(size_t)c * HH * WW]);
        } else {
            #pragma unroll
            for (int c = 0; c < CC; ++c) u.v[c] = __float2bfloat16(0.f);
        }
        uint4* dst = reinterpret_cast<uint4*>(Xt + (size_t)t * CC);
        dst[0] = u.q[0];
        dst[1] = u.q[1];
    } else if (t < NX + NW) {
        const int u  = t - NX;
        const int c  = u & 15;
        const int e  = (u >> 4) & 255;
        const int bt = u >> 12;
        const int tap = bt % 9;
        const int b   = bt / 9;
        Wg[u] = __float2bfloat16(emb[(size_t)indices[b * CC + c] * EMB_ROW + e * 9 + tap]);
    }
}

// ---------------- main: implicit-GEMM conv, LDS-coalesced stores ----------------
// grid: (BB, 32, 8)  block: 512 (8 waves). Block = 32e x 256w x 8h.
// Per h: each wave MFMAs its 32e x 32w tile -> LDS [32][256] f32 -> all waves
// store full contiguous 1KB (e,h) rows as dwordx4.
__global__ __launch_bounds__(512) void conv_mfma(
    const __bf16* __restrict__ Xt,      // [BB][HPAD][WPAD][CC]
    const __bf16* __restrict__ Wg,      // [BB][9][EE][CC]
    const float*  __restrict__ bias,    // [EE]
    float*        __restrict__ out)     // [BB][EE][HH][WW]
{
    __shared__ float lds[32 * 256];     // 32 KB

    const int b  = blockIdx.x;          // batch fastest -> XCD k handles batch k
    const int hc = blockIdx.y;
    const int ez = blockIdx.z;

    const int tid   = threadIdx.x;
    const int lane  = tid & 63;
    const int wid   = tid >> 6;         // 0..7
    const int l31   = lane & 31;
    const int lhalf = lane >> 5;

    const int e0 = ez * 32;
    const int w0 = wid * 32;
    const int h0 = hc * 8;

    // A fragments: 9 taps (identical across the 8 waves -> L1 broadcast)
    bf16x8 afrag[9];
    #pragma unroll
    for (int tap = 0; tap < 9; ++tap) {
        const __bf16* ap = Wg + ((size_t)(b * 9 + tap) * EE + (e0 + l31)) * CC + lhalf * 8;
        afrag[tap] = *reinterpret_cast<const bf16x8*>(ap);
    }

    // bias per C/D reg
    float bv[16];
    #pragma unroll
    for (int r = 0; r < 16; ++r) {
        const int erow = (r & 3) + 8 * (r >> 2) + 4 * lhalf;
        bv[r] = bias[e0 + erow];
    }

    for (int h = h0; h < h0 + 8; ++h) {
        f32x16 acc;
        #pragma unroll
        for (int r = 0; r < 16; ++r) acc[r] = bv[r];

        #pragma unroll
        for (int kh = 0; kh < 3; ++kh) {
            const __bf16* bp = Xt + ((size_t)(b * HPAD + (h + kh)) * WPAD + w0 + l31) * CC + lhalf * 8;
            #pragma unroll
            for (int kw = 0; kw < 3; ++kw) {
                bf16x8 bfrag = *reinterpret_cast<const bf16x8*>(bp + kw * CC);
                acc = __builtin_amdgcn_mfma_f32_32x32x16_bf16(afrag[kh * 3 + kw], bfrag, acc, 0, 0, 0);
            }
        }

        __syncthreads();                 // LDS tile free (prev h consumed)
        // scatter acc into LDS [erow][w]
        #pragma unroll
        for (int r = 0; r < 16; ++r) {
            const int erow = (r & 3) + 8 * (r >> 2) + 4 * lhalf;
            lds[erow * 256 + w0 + l31] = acc[r];
        }
        __syncthreads();                 // tile complete

        // coalesced store: wave wid handles e-rows {wid, 8+wid, 16+wid, 24+wid};
        // each instruction writes a full contiguous 1KB row (64 lanes x 16B)
        #pragma unroll
        for (int i = 0; i < 4; ++i) {
            const int e = i * 8 + wid;
            const f32x4 v = *reinterpret_cast<const f32x4*>(&lds[e * 256 + lane * 4]);
            __builtin_nontemporal_store(v,
                reinterpret_cast<f32x4*>(&out[((size_t)(b * EE + e0 + e) * HH + h) * WW + lane * 4]));
        }
    }
}

// ---------------- fallback: f32 direct conv (if ws too small) ----------------
#define EBLK 4
#define RBLK 4
__global__ __launch_bounds__(256) void conv_emb_f32(
    const float* __restrict__ x, const int* __restrict__ indices,
    const float* __restrict__ emb, const float* __restrict__ bias,
    float* __restrict__ out)
{
    const int w  = threadIdx.x;
    const int h0 = blockIdx.x * RBLK;
    const int e0 = blockIdx.y * EBLK;
    const int b  = blockIdx.z;

    float acc[RBLK][EBLK];
    #pragma unroll
    for (int r = 0; r < RBLK; ++r)
        #pragma unroll
        for (int e = 0; e < EBLK; ++e) acc[r][e] = 0.f;

    #pragma unroll 1
    for (int c = 0; c < CC; ++c) {
        const float* xp = x + (size_t)(b * CC + c) * HH * WW;
        float xv[RBLK + 2][3];
        #pragma unroll
        for (int ir = 0; ir < RBLK + 2; ++ir) {
            const int h = h0 + ir - 1;
            if (h >= 0 && h < HH) {
                const float* row = xp + (size_t)h * WW;
                xv[ir][1] = row[w];
                xv[ir][0] = (w > 0)      ? row[w - 1] : 0.f;
                xv[ir][2] = (w < WW - 1) ? row[w + 1] : 0.f;
            } else {
                xv[ir][0] = 0.f; xv[ir][1] = 0.f; xv[ir][2] = 0.f;
            }
        }
        const int idx = indices[b * CC + c];
        const float* wp = emb + (size_t)idx * EMB_ROW + e0 * 9;
        #pragma unroll
        for (int e = 0; e < EBLK; ++e)
            #pragma unroll
            for (int kh = 0; kh < 3; ++kh)
                #pragma unroll
                for (int kw = 0; kw < 3; ++kw) {
                    const float wv = wp[e * 9 + kh * 3 + kw];
                    #pragma unroll
                    for (int r = 0; r < RBLK; ++r)
                        acc[r][e] += xv[r + kh][kw] * wv;
                }
    }
    #pragma unroll
    for (int e = 0; e < EBLK; ++e) {
        const float bvv = bias[e0 + e];
        #pragma unroll
        for (int r = 0; r < RBLK; ++r)
            out[((size_t)(b * EE + e0 + e) * HH + (h0 + r)) * WW + w] = acc[r][e] + bvv;
    }
}

extern "C" void kernel_launch(void* const* d_in, const int* in_sizes, int n_in,
                              void* d_out, int out_size, void* d_ws, size_t ws_size,
                              hipStream_t stream) {
    const float* x       = (const float*)d_in[0];
    const int*   indices = (const int*)  d_in[1];
    const float* emb     = (const float*)d_in[2];
    const float* bias    = (const float*)d_in[3];
    float*       out     = (float*)d_out;

    if (ws_size < (size_t)WS_NEEDED) {
        dim3 grid(HH / RBLK, EE / EBLK, BB);
        conv_emb_f32<<<grid, dim3(256), 0, stream>>>(x, indices, emb, bias, out);
        return;
    }

    __hip_bfloat16* Xt = (__hip_bfloat16*)d_ws;
    __hip_bfloat16* Wg = (__hip_bfloat16*)((char*)d_ws + XT_BYTES);

    prep_all<<<dim3(PREP_BLOCKS), dim3(256), 0, stream>>>(x, indices, emb, Xt, Wg);

    conv_mfma<<<dim3(BB, 32, 8), dim3(512), 0, stream>>>(
        (const __bf16*)Xt, (const __bf16*)Wg, bias, out);
}

// Round 7
// 119.039 us; speedup vs baseline: 1.1261x; 1.0034x over previous
//
#include <hip/hip_runtime.h>
#include <hip/hip_bf16.h>

#define BB 8
#define CC 16
#define EE 256
#define HH 256
#define WW 256
#define HPAD 258
#define WPAD 258
#define EMB_ROW (EE*9)

typedef __attribute__((ext_vector_type(8)))  __bf16 bf16x8;
typedef __attribute__((ext_vector_type(16))) float  f32x16;
typedef __attribute__((ext_vector_type(4)))  float  f32x4;

// ---- ws layout ----
#define XT_BYTES  17040384            // [BB][HPAD][WPAD][CC] bf16
#define WS_NEEDED (XT_BYTES + 589824) // + [BB][9][EE][CC] bf16

#define NX (BB*HPAD*WPAD)
#define NW (BB*9*EE*CC)
#define PREP_BLOCKS ((NX + NW + 255) / 256)

// ---------------- merged prep: x-transpose + weight gather ----------------
__global__ __launch_bounds__(256) void prep_all(const float* __restrict__ x,
                                                const int* __restrict__ indices,
                                                const float* __restrict__ emb,
                                                __hip_bfloat16* __restrict__ Xt,
                                                __hip_bfloat16* __restrict__ Wg) {
    const int t = blockIdx.x * 256 + threadIdx.x;
    if (t < NX) {
        const int wp = t % WPAD;
        const int r  = t / WPAD;
        const int hp = r % HPAD;
        const int b  = r / HPAD;
        union { __hip_bfloat16 v[16]; uint4 q[2]; } u;
        if (hp >= 1 && hp <= HH && wp >= 1 && wp <= WW) {
            const float* xp = x + (size_t)b * CC * HH * WW + (size_t)(hp - 1) * WW + (wp - 1);
            #pragma unroll
            for (int c = 0; c < CC; ++c)
                u.v[c] = __float2bfloat16(xp[(size_t)c * HH * WW]);
        } else {
            #pragma unroll
            for (int c = 0; c < CC; ++c) u.v[c] = __float2bfloat16(0.f);
        }
        uint4* dst = reinterpret_cast<uint4*>(Xt + (size_t)t * CC);
        dst[0] = u.q[0];
        dst[1] = u.q[1];
    } else if (t < NX + NW) {
        const int u  = t - NX;
        const int c  = u & 15;
        const int e  = (u >> 4) & 255;
        const int bt = u >> 12;
        const int tap = bt % 9;
        const int b   = bt / 9;
        Wg[u] = __float2bfloat16(emb[(size_t)indices[b * CC + c] * EMB_ROW + e * 9 + tap]);
    }
}

// ---------------- main: implicit-GEMM conv, double-buffered LDS epilogue ----------------
// grid: (BB, 16, 8)  block: 512 (8 waves). Block = 32e x 256w x 16h.
// Per h: waves MFMA their 32e x 32w tile -> scatter to lds[p] -> ONE barrier ->
// read back full contiguous 1KB (e,h) rows, nt-store. p flips each h, so
// scatter(h+1) never touches the buffer being stored(h).
__global__ __launch_bounds__(512) void conv_mfma(
    const __bf16* __restrict__ Xt,      // [BB][HPAD][WPAD][CC]
    const __bf16* __restrict__ Wg,      // [BB][9][EE][CC]
    const float*  __restrict__ bias,    // [EE]
    float*        __restrict__ out)     // [BB][EE][HH][WW]
{
    __shared__ float lds[2][32 * 256];  // 2 x 32 KB

    const int b  = blockIdx.x;          // batch fastest -> XCD k handles batch k
    const int hc = blockIdx.y;
    const int ez = blockIdx.z;

    const int tid   = threadIdx.x;
    const int lane  = tid & 63;
    const int wid   = tid >> 6;         // 0..7
    const int l31   = lane & 31;
    const int lhalf = lane >> 5;

    const int e0 = ez * 32;
    const int w0 = wid * 32;
    const int h0 = hc * 16;

    // A fragments: 9 taps (identical across the 8 waves -> L1 broadcast)
    bf16x8 afrag[9];
    #pragma unroll
    for (int tap = 0; tap < 9; ++tap) {
        const __bf16* ap = Wg + ((size_t)(b * 9 + tap) * EE + (e0 + l31)) * CC + lhalf * 8;
        afrag[tap] = *reinterpret_cast<const bf16x8*>(ap);
    }

    // bias per C/D reg
    float bv[16];
    #pragma unroll
    for (int r = 0; r < 16; ++r) {
        const int erow = (r & 3) + 8 * (r >> 2) + 4 * lhalf;
        bv[r] = bias[e0 + erow];
    }

    int p = 0;
    for (int h = h0; h < h0 + 16; ++h, p ^= 1) {
        f32x16 acc;
        #pragma unroll
        for (int r = 0; r < 16; ++r) acc[r] = bv[r];

        #pragma unroll
        for (int kh = 0; kh < 3; ++kh) {
            const __bf16* bp = Xt + ((size_t)(b * HPAD + (h + kh)) * WPAD + w0 + l31) * CC + lhalf * 8;
            #pragma unroll
            for (int kw = 0; kw < 3; ++kw) {
                bf16x8 bfrag = *reinterpret_cast<const bf16x8*>(bp + kw * CC);
                acc = __builtin_amdgcn_mfma_f32_32x32x16_bf16(afrag[kh * 3 + kw], bfrag, acc, 0, 0, 0);
            }
        }

        // scatter acc into lds[p][erow][w]  (2-way bank alias only -> free)
        #pragma unroll
        for (int r = 0; r < 16; ++r) {
            const int erow = (r & 3) + 8 * (r >> 2) + 4 * lhalf;
            lds[p][erow * 256 + w0 + l31] = acc[r];
        }
        __syncthreads();                 // single barrier per h

        // coalesced store: wave wid stores e-rows wid*4 .. wid*4+3;
        // each instruction writes a full contiguous 1KB row (64 lanes x 16B)
        #pragma unroll
        for (int i = 0; i < 4; ++i) {
            const int e = wid * 4 + i;
            const f32x4 v = *reinterpret_cast<const f32x4*>(&lds[p][e * 256 + lane * 4]);
            __builtin_nontemporal_store(v,
                reinterpret_cast<f32x4*>(&out[((size_t)(b * EE + e0 + e) * HH + h) * WW + lane * 4]));
        }
    }
}

// ---------------- fallback: f32 direct conv (if ws too small) ----------------
#define EBLK 4
#define RBLK 4
__global__ __launch_bounds__(256) void conv_emb_f32(
    const float* __restrict__ x, const int* __restrict__ indices,
    const float* __restrict__ emb, const float* __restrict__ bias,
    float* __restrict__ out)
{
    const int w  = threadIdx.x;
    const int h0 = blockIdx.x * RBLK;
    const int e0 = blockIdx.y * EBLK;
    const int b  = blockIdx.z;

    float acc[RBLK][EBLK];
    #pragma unroll
    for (int r = 0; r < RBLK; ++r)
        #pragma unroll
        for (int e = 0; e < EBLK; ++e) acc[r][e] = 0.f;

    #pragma unroll 1
    for (int c = 0; c < CC; ++c) {
        const float* xp = x + (size_t)(b * CC + c) * HH * WW;
        float xv[RBLK + 2][3];
        #pragma unroll
        for (int ir = 0; ir < RBLK + 2; ++ir) {
            const int h = h0 + ir - 1;
            if (h >= 0 && h < HH) {
                const float* row = xp + (size_t)h * WW;
                xv[ir][1] = row[w];
                xv[ir][0] = (w > 0)      ? row[w - 1] : 0.f;
                xv[ir][2] = (w < WW - 1) ? row[w + 1] : 0.f;
            } else {
                xv[ir][0] = 0.f; xv[ir][1] = 0.f; xv[ir][2] = 0.f;
            }
        }
        const int idx = indices[b * CC + c];
        const float* wp = emb + (size_t)idx * EMB_ROW + e0 * 9;
        #pragma unroll
        for (int e = 0; e < EBLK; ++e)
            #pragma unroll
            for (int kh = 0; kh < 3; ++kh)
                #pragma unroll
                for (int kw = 0; kw < 3; ++kw) {
                    const float wv = wp[e * 9 + kh * 3 + kw];
                    #pragma unroll
                    for (int r = 0; r < RBLK; ++r)
                        acc[r][e] += xv[r + kh][kw] * wv;
                }
    }
    #pragma unroll
    for (int e = 0; e < EBLK; ++e) {
        const float bvv = bias[e0 + e];
        #pragma unroll
        for (int r = 0; r < RBLK; ++r)
            out[((size_t)(b * EE + e0 + e) * HH + (h0 + r)) * WW + w] = acc[r][e] + bvv;
    }
}

extern "C" void kernel_launch(void* const* d_in, const int* in_sizes, int n_in,
                              void* d_out, int out_size, void* d_ws, size_t ws_size,
                              hipStream_t stream) {
    const float* x       = (const float*)d_in[0];
    const int*   indices = (const int*)  d_in[1];
    const float* emb     = (const float*)d_in[2];
    const float* bias    = (const float*)d_in[3];
    float*       out     = (float*)d_out;

    if (ws_size < (size_t)WS_NEEDED) {
        dim3 grid(HH / RBLK, EE / EBLK, BB);
        conv_emb_f32<<<grid, dim3(256), 0, stream>>>(x, indices, emb, bias, out);
        return;
    }

    __hip_bfloat16* Xt = (__hip_bfloat16*)d_ws;
    __hip_bfloat16* Wg = (__hip_bfloat16*)((char*)d_ws + XT_BYTES);

    prep_all<<<dim3(PREP_BLOCKS), dim3(256), 0, stream>>>(x, indices, emb, Xt, Wg);

    conv_mfma<<<dim3(BB, 16, 8), dim3(512), 0, stream>>>(
        (const __bf16*)Xt, (const __bf16*)Wg, bias, out);
}